// Round 1
// baseline (2789.919 us; speedup 1.0000x reference)
//
#include <hip/hip_runtime.h>
#include <hip/hip_bf16.h>

#define M_ROWS 16384
#define K_IN   2048
#define N_OUT  8192
#define OG     12            // outputs per structural group
#define NG     683           // ceil(8192/12)
#define KUMAX  64            // capacity of per-group union k-list
#define WST    16            // Wd row stride (12 used + 4 pad, 64B aligned)

// ---------------- transpose: x[M][K] f32 -> xT[K][M] bf16 ----------------
__global__ void ninja_xpose(const float* __restrict__ x, __hip_bfloat16* __restrict__ xT) {
    __shared__ float tile[64][65];
    int mt = blockIdx.x, kt = blockIdx.y;
    int t = threadIdx.x;
    int c = t & 63;      // inner (coalesced) index
    int r4 = t >> 6;     // 0..3
#pragma unroll
    for (int i = 0; i < 16; i++) {
        int r = r4 + i * 4;
        tile[r][c] = x[(size_t)(mt * 64 + r) * K_IN + kt * 64 + c];
    }
    __syncthreads();
#pragma unroll
    for (int i = 0; i < 16; i++) {
        int r = r4 + i * 4;  // k-local
        xT[(size_t)(kt * 64 + r) * M_ROWS + mt * 64 + c] = __float2bfloat16(tile[c][r]);
    }
}

// ---------------- prep: build per-group union k-list + dense weight panel ----------------
__global__ void ninja_prep(const float* __restrict__ mask, const float* __restrict__ W,
                           int* __restrict__ klist, int* __restrict__ kuArr,
                           float* __restrict__ Wd) {
    int g = blockIdx.x, t = threadIdx.x;
    int o0 = g * OG;
    int no = min(OG, N_OUT - o0);
    __shared__ int cnt;
    __shared__ int kl[KUMAX];
    if (t == 0) cnt = 0;
    __syncthreads();
    for (int k = t; k < K_IN; k += 256) {
        bool any = false;
        for (int oo = 0; oo < no; oo++)
            any = any || (mask[(size_t)(o0 + oo) * K_IN + k] != 0.0f);
        if (any) {
            int p = atomicAdd(&cnt, 1);
            if (p < KUMAX) kl[p] = k;
        }
    }
    __syncthreads();
    int c = cnt;
    if (c > KUMAX) {                 // dense group (contains o=0)
        if (t == 0) kuArr[g] = -1;
        return;
    }
    int kup = (c + 3) & ~3;          // pad to multiple of 4
    for (int j = c + t; j < kup; j += 256) kl[j] = 0;   // pad entries -> k=0, weight 0
    __syncthreads();
    if (t == 0) kuArr[g] = kup;
    for (int j = t; j < kup; j += 256) klist[g * KUMAX + j] = kl[j];
    for (int idx = t; idx < kup * WST; idx += 256) {
        int jk = idx / WST, oo = idx % WST;
        float v = 0.0f;
        if (jk < c && oo < no) {
            size_t p = (size_t)(o0 + oo) * K_IN + kl[jk];
            v = mask[p] * W[p];
        }
        Wd[(size_t)(g * KUMAX + jk) * WST + oo] = v;
    }
}

// ---------------- main: per (group, m-tile of 512) ----------------
__global__ __launch_bounds__(256)
void ninja_main(const __hip_bfloat16* __restrict__ xT,
                const float* __restrict__ mask, const float* __restrict__ W,
                const float* __restrict__ bias,
                const int* __restrict__ klist, const int* __restrict__ kuArr,
                const float* __restrict__ Wd, float* __restrict__ y) {
    int g = blockIdx.x, mt = blockIdx.y, t = threadIdx.x;
    int o0 = g * OG;
    int no = min(OG, N_OUT - o0);
    int m = mt * 512 + t;            // thread handles m and m+256
    float accA[OG], accB[OG];
#pragma unroll
    for (int i = 0; i < OG; i++) { accA[i] = 0.0f; accB[i] = 0.0f; }

    int ku = kuArr[g];
    if (ku >= 0) {
        const int* kl = klist + g * KUMAX;
        const float* wd = Wd + (size_t)g * KUMAX * WST;
        for (int jk = 0; jk < ku; jk++) {
            int k = kl[jk];                                   // wave-uniform
            float xa = __bfloat162float(xT[(size_t)k * M_ROWS + m]);
            float xb = __bfloat162float(xT[(size_t)k * M_ROWS + m + 256]);
            const float* w = wd + jk * WST;                   // wave-uniform row
#pragma unroll
            for (int oo = 0; oo < OG; oo++) {
                float wv = w[oo];
                accA[oo] = fmaf(xa, wv, accA[oo]);
                accB[oo] = fmaf(xb, wv, accB[oo]);
            }
        }
    } else {
        // dense group (contains output 0): loop all k, weights are wave-uniform scalar loads
        for (int k = 0; k < K_IN; k++) {
            float xa = __bfloat162float(xT[(size_t)k * M_ROWS + m]);
            float xb = __bfloat162float(xT[(size_t)k * M_ROWS + m + 256]);
#pragma unroll
            for (int oo = 0; oo < OG; oo++) {
                size_t p = (size_t)(o0 + oo) * K_IN + k;
                float wv = (oo < no) ? mask[p] * W[p] : 0.0f;
                accA[oo] = fmaf(xa, wv, accA[oo]);
                accB[oo] = fmaf(xb, wv, accB[oo]);
            }
        }
    }

    size_t ybA = (size_t)m * N_OUT + o0;
    size_t ybB = (size_t)(m + 256) * N_OUT + o0;
    if (no == OG) {
#pragma unroll
        for (int i = 0; i < 6; i++) {
            float b0 = bias[o0 + 2 * i], b1 = bias[o0 + 2 * i + 1];
            *reinterpret_cast<float2*>(y + ybA + 2 * i) =
                make_float2(accA[2 * i] + b0, accA[2 * i + 1] + b1);
            *reinterpret_cast<float2*>(y + ybB + 2 * i) =
                make_float2(accB[2 * i] + b0, accB[2 * i + 1] + b1);
        }
    } else {
        for (int oo = 0; oo < no; oo++) {
            float b = bias[o0 + oo];
            y[ybA + oo] = accA[oo] + b;
            y[ybB + oo] = accB[oo] + b;
        }
    }
}

// ---------------- fallback: plain tiled dense GEMM (used only if ws too small) ----------------
__global__ void ninja_fallback(const float* __restrict__ x, const float* __restrict__ W,
                               const float* __restrict__ bias, const float* __restrict__ mask,
                               float* __restrict__ y) {
    int ot = blockIdx.x, mtile = blockIdx.y, t = threadIdx.x;
    int mloc = t & 63;
    int q = t >> 6;                 // wave id 0..3
    int m = mtile * 64 + mloc;
    int obase = ot * 64 + q * 16;
    float acc[16];
#pragma unroll
    for (int i = 0; i < 16; i++) acc[i] = 0.0f;
    __shared__ float xs[32][65];
    for (int kt = 0; kt < K_IN; kt += 32) {
#pragma unroll
        for (int j = 0; j < 8; j++) {
            int idx = t + j * 256;
            int r = idx >> 5, cc = idx & 31;
            xs[cc][r] = x[(size_t)(mtile * 64 + r) * K_IN + kt + cc];
        }
        __syncthreads();
        for (int kk = 0; kk < 32; kk++) {
            float xv = xs[kk][mloc];
#pragma unroll
            for (int i = 0; i < 16; i++) {
                size_t p = (size_t)(obase + i) * K_IN + kt + kk;  // wave-uniform
                acc[i] = fmaf(xv, mask[p] * W[p], acc[i]);
            }
        }
        __syncthreads();
    }
#pragma unroll
    for (int i = 0; i < 16; i++) acc[i] += bias[obase + i];
    float4* yp = reinterpret_cast<float4*>(y + (size_t)m * N_OUT + obase);
#pragma unroll
    for (int i = 0; i < 4; i++)
        yp[i] = make_float4(acc[4 * i], acc[4 * i + 1], acc[4 * i + 2], acc[4 * i + 3]);
}

extern "C" void kernel_launch(void* const* d_in, const int* in_sizes, int n_in,
                              void* d_out, int out_size, void* d_ws, size_t ws_size,
                              hipStream_t stream) {
    const float* x    = (const float*)d_in[0];
    const float* W    = (const float*)d_in[1];
    const float* bias = (const float*)d_in[2];
    const float* mask = (const float*)d_in[3];
    float* y = (float*)d_out;

    size_t xT_bytes    = (size_t)K_IN * M_ROWS * sizeof(__hip_bfloat16);   // 64 MB
    size_t klist_off   = xT_bytes;
    size_t klist_bytes = (size_t)NG * KUMAX * sizeof(int);
    size_t ku_off      = klist_off + klist_bytes;
    size_t ku_bytes    = ((size_t)NG * sizeof(int) + 255) & ~(size_t)255;
    size_t wd_off      = ku_off + ku_bytes;
    size_t wd_bytes    = (size_t)NG * KUMAX * WST * sizeof(float);
    size_t needed      = wd_off + wd_bytes;

    if (ws_size < needed) {
        ninja_fallback<<<dim3(N_OUT / 64, M_ROWS / 64), 256, 0, stream>>>(x, W, bias, mask, y);
        return;
    }

    char* ws = (char*)d_ws;
    __hip_bfloat16* xT = (__hip_bfloat16*)ws;
    int*   klist = (int*)(ws + klist_off);
    int*   kuArr = (int*)(ws + ku_off);
    float* Wd    = (float*)(ws + wd_off);

    ninja_xpose<<<dim3(M_ROWS / 64, K_IN / 64), 256, 0, stream>>>(x, xT);
    ninja_prep<<<dim3(NG), 256, 0, stream>>>(mask, W, klist, kuArr, Wd);
    ninja_main<<<dim3(NG, M_ROWS / 512), 256, 0, stream>>>(xT, mask, W, bias, klist, kuArr, Wd, y);
}